// Round 10
// baseline (120.699 us; speedup 1.0000x reference)
//
#include <hip/hip_runtime.h>

typedef __bf16 bf16x8 __attribute__((ext_vector_type(8)));
typedef float f32x4 __attribute__((ext_vector_type(4)));
typedef float f32x16 __attribute__((ext_vector_type(16)));

#define CC 256
#define HH 48
#define WW 64
#define HW (HH * WW)
#define NB 8
#define GW 21

// ---------------------------------------------------------------------------
// Prepass (unchanged): BOTH inputs -> MFMA-fragment PARITY order
//   [b][y][cblk=c>>3][p=x&1][x2=x>>1][c&7] bf16
// in1 scaled by 2^-8 (exact in bf16) to fold the /sumelems.
// ---------------------------------------------------------------------------
__global__ __launch_bounds__(256) void prep_kernel(const float* __restrict__ in1,
                                                   const float* __restrict__ in2,
                                                   unsigned short* __restrict__ o1,
                                                   unsigned short* __restrict__ o2)
{
    __shared__ float lds[CC * 33];
    int blk  = blockIdx.x;
    int sel  = (blk >= 768);
    int blk2 = sel ? blk - 768 : blk;
    int b  = blk2 & 7;
    int st = blk2 >> 3;
    int s0 = st * 32;
    const float* src = sel ? in2 : in1;
    unsigned short* dst = sel ? o2 : o1;
    float scale = sel ? 1.0f : (1.0f / 256.0f);

    int t = threadIdx.x;
    int sidx  = t & 31;
    int cbase = t >> 5;
    const float* sb = src + (size_t)b * CC * HW + s0;
    #pragma unroll
    for (int p = 0; p < 32; ++p) {
        int c = cbase + p * 8;
        lds[c * 33 + sidx] = sb[(size_t)c * HW + sidx] * scale;
    }
    __syncthreads();

    int y  = s0 >> 6;
    int xb = s0 & 63;
    int s  = t & 31;
    int c8 = t >> 5;
    unsigned short* db = dst + (size_t)(b * HH + y) * 32 * 64 * 8;
    int x = xb + s;
    int xoff = (x & 1) * 32 + (x >> 1);
    #pragma unroll
    for (int it = 0; it < 4; ++it) {
        int cblk = it * 8 + c8;
        unsigned dw[4];
        #pragma unroll
        for (int d = 0; d < 4; ++d) {
            unsigned u0 = __builtin_bit_cast(unsigned, lds[(cblk * 8 + 2 * d) * 33 + s]);
            u0 += 0x7fffu + ((u0 >> 16) & 1u);
            unsigned u1 = __builtin_bit_cast(unsigned, lds[(cblk * 8 + 2 * d + 1) * 33 + s]);
            u1 += 0x7fffu + ((u1 >> 16) & 1u);
            dw[d] = (u0 >> 16) | (u1 & 0xffff0000u);
        }
        *(uint4*)(db + ((size_t)cblk * 64 + xoff) * 8) =
            make_uint4(dw[0], dw[1], dw[2], dw[3]);
    }
}

// ---------------------------------------------------------------------------
// Main (R17): WRITE-CONTIGUOUS restructure. Seven read-side variants moved
// corr <=2% while L2 flow varied 2x -> the invariant ~20us matches the ONE
// never-varied element: per-wave nontemporal stores of 256B granules at
// 12KB stride (new DRAM page per granule -> ~30% write efficiency -> ~18us
// for the 43MB output). This kernel stores CONTIGUOUSLY:
//  - block = (b, dy, yb): 4 waves, wave w computes yo = 8*yb + 2w + i
//    (one (A,B) row pair per yo, parity GEMM, proven depth-4/dist-3 rings).
//  - band-extract writes into block-shared stage[21 dx][8 yo][64 x] LDS,
//    ONE barrier, then cooperative NT stores: 21 chunks x 2KB contiguous
//    (vs 256B scattered) -> page-local DRAM writes.
//  - reads stay direct-from-global (L2-resident, dy-minor order => ~1.7MB
//    per-XCD window); no early returns (barrier-safe; OOB ysrc -> zeros).
// Grid 8 x 21 x 6 = 1008 blocks (3.9/CU); LDS 78KB -> 2 blocks/CU = 8 waves.
// ---------------------------------------------------------------------------
__global__ __launch_bounds__(256, 2) void corr_kernel(const unsigned short* __restrict__ in1F,
                                                      const unsigned short* __restrict__ in2F,
                                                      float* __restrict__ out)
{
    __shared__ float dts[4][2304];               // per-wave D^T [pe][32 ce][36 xe]
    __shared__ float stage[GW * 8 * WW];         // [dx][8 yo][64 x] = 43008 B

    int blk = blockIdx.x;
    int b   = blk & 7;                           // batch == XCD affinity
    int r   = blk >> 3;                          // dy-minor: L2 locality window
    int dy  = r % GW;                            // 0..20
    int yb  = r / GW;                            // 0..5 (8-row band)
    int soff = 2 * dy - 20;                      // ysrc = yo + soff

    int tid  = threadIdx.x;
    int w    = tid >> 6;                         // 0..3
    int lane = tid & 63;
    int l31  = lane & 31;
    int q2   = lane >> 5;
    int lofs = q2 * 512 + l31 * 8;               // fragment base (ushort units)

    float* dtw = dts[w];
    int xe = lane >> 1;
    int pe = lane & 1;

    #pragma unroll 1
    for (int i = 0; i < 2; ++i) {
        int yloc = 2 * w + i;                    // 0..7
        int yo   = 8 * yb + yloc;                // 0..47
        int ys   = yo + soff;
        bool vs  = (ys >= 0) && (ys < HH);       // wave-uniform

        f32x16 acc[2];
        acc[0] = (f32x16)(0.0f);
        acc[1] = (f32x16)(0.0f);

        if (vs) {
            const unsigned short* ar = in1F + (size_t)(b * HH + yo) * 16384 + lofs;
            const unsigned short* br = in2F + (size_t)(b * HH + ys) * 16384 + lofs;

            // ---- depth-4 / distance-3 rings for A and B (proven pattern) ----
            bf16x8 Ab[4][2], Bb[4][2];
            #pragma unroll
            for (int s = 0; s < 3; ++s)
                #pragma unroll
                for (int p = 0; p < 2; ++p) {
                    Ab[s][p] = *(const bf16x8*)(ar + (size_t)s * 1024 + p * 256);
                    Bb[s][p] = *(const bf16x8*)(br + (size_t)s * 1024 + p * 256);
                }

            #pragma unroll
            for (int kk = 0; kk < 16; ++kk) {
                if (kk < 13) {                   // refill slot kk+3, 3 iters ahead
                    #pragma unroll
                    for (int p = 0; p < 2; ++p) {
                        Ab[(kk + 3) & 3][p] =
                            *(const bf16x8*)(ar + (size_t)(kk + 3) * 1024 + p * 256);
                        Bb[(kk + 3) & 3][p] =
                            *(const bf16x8*)(br + (size_t)(kk + 3) * 1024 + p * 256);
                    }
                }
                #pragma unroll
                for (int p = 0; p < 2; ++p)
                    acc[p] = __builtin_amdgcn_mfma_f32_32x32x16_bf16(
                        Ab[kk & 3][p], Bb[kk & 3][p], acc[p], 0, 0, 0);
            }
        }

        // D^T dump (wave-private) + band extract into the block stage buffer.
        // 32x32 C layout: col = l31 (n = ce), row = (r&3)+8*(r>>2)+4*q2 (m = xe).
        #pragma unroll
        for (int p = 0; p < 2; ++p)
            #pragma unroll
            for (int rq = 0; rq < 4; ++rq) {
                f32x4 v = { acc[p][4 * rq], acc[p][4 * rq + 1],
                            acc[p][4 * rq + 2], acc[p][4 * rq + 3] };
                *(f32x4*)(dtw + (size_t)(p * 32 + l31) * 36 + rq * 8 + q2 * 4) = v;
            }
        #pragma unroll
        for (int jx = 0; jx < GW; ++jx) {
            int ce = xe + jx - 10;               // x = 2*xe+pe, colx = 2*ce+pe
            float val = (vs && ce >= 0 && ce < 32)
                      ? dtw[(size_t)(pe * 32 + ce) * 36 + xe] : 0.0f;
            stage[jx * 512 + yloc * 64 + lane] = val;
        }
    }

    __syncthreads();                             // all stage slices complete

    // Cooperative contiguous output: 21 chunks of 2KB (one per dx), each
    // chunk = rows [8*yb, 8*yb+8) x 64 x of channel (dy*21+dx). NT f32x4.
    size_t obase = ((size_t)(b * 441 + dy * GW) * HH + yb * 8) * WW;
    for (int s = tid; s < GW * 128; s += 256) {  // 128 f32x4 slots per chunk
        int dxi = s >> 7;
        int rem = s & 127;
        f32x4 v = *(const f32x4*)(stage + dxi * 512 + rem * 4);
        __builtin_nontemporal_store(v, (f32x4*)(out + obase + (size_t)dxi * HW + rem * 4));
    }
}

extern "C" void kernel_launch(void* const* d_in, const int* in_sizes, int n_in,
                              void* d_out, int out_size, void* d_ws, size_t ws_size,
                              hipStream_t stream)
{
    (void)in_sizes; (void)n_in; (void)out_size; (void)ws_size;
    const float* in1 = (const float*)d_in[0];
    const float* in2 = (const float*)d_in[1];
    float* out = (float*)d_out;

    unsigned short* in1F = (unsigned short*)d_ws;                 // 12.6 MB
    unsigned short* in2F = in1F + (size_t)NB * HW * CC;           // 12.6 MB

    prep_kernel<<<dim3(1536), dim3(256), 0, stream>>>(in1, in2, in1F, in2F);
    corr_kernel<<<dim3(NB * GW * 6), dim3(256), 0, stream>>>(in1F, in2F, out);
}

// Round 11
// 115.053 us; speedup vs baseline: 1.0491x; 1.0491x over previous
//
#include <hip/hip_runtime.h>

typedef __bf16 bf16x8 __attribute__((ext_vector_type(8)));
typedef float f32x4 __attribute__((ext_vector_type(4)));
typedef float f32x16 __attribute__((ext_vector_type(16)));

#define CC 256
#define HH 48
#define WW 64
#define HW (HH * WW)
#define NB 8
#define GW 21

// ---------------------------------------------------------------------------
// Prepass: BOTH inputs -> MFMA-fragment PARITY order
//   [b][y][cblk=c>>3][p=x&1][x2=x>>1][c&7] bf16
// in1 scaled by 2^-8 (exact in bf16) to fold the /sumelems.
// ---------------------------------------------------------------------------
__global__ __launch_bounds__(256) void prep_kernel(const float* __restrict__ in1,
                                                   const float* __restrict__ in2,
                                                   unsigned short* __restrict__ o1,
                                                   unsigned short* __restrict__ o2)
{
    __shared__ float lds[CC * 33];
    int blk  = blockIdx.x;
    int sel  = (blk >= 768);
    int blk2 = sel ? blk - 768 : blk;
    int b  = blk2 & 7;
    int st = blk2 >> 3;
    int s0 = st * 32;
    const float* src = sel ? in2 : in1;
    unsigned short* dst = sel ? o2 : o1;
    float scale = sel ? 1.0f : (1.0f / 256.0f);

    int t = threadIdx.x;
    int sidx  = t & 31;
    int cbase = t >> 5;
    const float* sb = src + (size_t)b * CC * HW + s0;
    #pragma unroll
    for (int p = 0; p < 32; ++p) {
        int c = cbase + p * 8;
        lds[c * 33 + sidx] = sb[(size_t)c * HW + sidx] * scale;
    }
    __syncthreads();

    int y  = s0 >> 6;
    int xb = s0 & 63;
    int s  = t & 31;
    int c8 = t >> 5;
    unsigned short* db = dst + (size_t)(b * HH + y) * 32 * 64 * 8;
    int x = xb + s;
    int xoff = (x & 1) * 32 + (x >> 1);
    #pragma unroll
    for (int it = 0; it < 4; ++it) {
        int cblk = it * 8 + c8;
        unsigned dw[4];
        #pragma unroll
        for (int d = 0; d < 4; ++d) {
            unsigned u0 = __builtin_bit_cast(unsigned, lds[(cblk * 8 + 2 * d) * 33 + s]);
            u0 += 0x7fffu + ((u0 >> 16) & 1u);
            unsigned u1 = __builtin_bit_cast(unsigned, lds[(cblk * 8 + 2 * d + 1) * 33 + s]);
            u1 += 0x7fffu + ((u1 >> 16) & 1u);
            dw[d] = (u0 >> 16) | (u1 & 0xffff0000u);
        }
        *(uint4*)(db + ((size_t)cblk * 64 + xoff) * 8) =
            make_uint4(dw[0], dw[1], dw[2], dw[3]);
    }
}

// ---------------------------------------------------------------------------
// Main (R18 = R16, the best-measured variant, 113.7us): R14's zero-barrier
// independent-wave body, regrouped so waves SHARING B rows co-reside on one
// CU (L1 reuse). block = (b, yi, t), 4 waves, wave w -> q = 4t + w. All 4
// waves read the SAME two B rows (ys0, ys1 depend only on yi) at nearly the
// same time -> ~3/4 of B reads L1-hit -> L2 volume ~380MB, while waves stay
// fully independent (no barriers; wave-private D^T LDS; idle waves exit
// immediately). LDS 36.9KB/block, launch_bounds(256,2) -> 2-3 blocks/CU.
// Grid 8b x 88 yi x 3 t = 2112 blocks; blocks of one yi are stride-8 apart
// -> same XCD (b = blk&7 affinity preserved).
// Session ledger (R8-R17): parity-split GEMM -32 MFMA/wave (R8); L1
// B-sharing -2.2us (R16); refuted: A/B-traffic cuts, prefetch depth,
// staging path, barrier/phase structure, write-page locality (R17 +7us).
// ---------------------------------------------------------------------------
__global__ __launch_bounds__(256, 2) void corr_kernel(const unsigned short* __restrict__ in1F,
                                                      const unsigned short* __restrict__ in2F,
                                                      float* __restrict__ out)
{
    __shared__ float dts[4][2304];               // per-wave [pe][32 ce][36 xe]

    int blk = blockIdx.x;
    int b   = blk & 7;                           // batch == XCD affinity
    int r   = blk >> 3;                          // ysrc-major
    int yi  = r / 3;                             // 0..87
    int t   = r - yi * 3;                        // 0..2
    int ys0 = yi - 20;
    int ys1 = ys0 + 2;

    int tid  = threadIdx.x;
    int w    = tid >> 6;                         // 0..3
    int lane = tid & 63;
    int q    = 4 * t + w;                        // 0..11
    int yo   = ys0 + 20 - 4 * q;                 // output row (also A row)

    // idle waves exit immediately -- legal: no barriers in this kernel
    if (q > 10 || yo < 0 || yo >= HH) return;

    bool vs_[2];
    vs_[0] = (ys0 >= 0) && (ys0 < HH);
    vs_[1] = (ys1 >= 0) && (ys1 < HH);
    int j0 = 2 * q;

    int l31 = lane & 31;
    int q2  = lane >> 5;
    int lofs = q2 * 512 + l31 * 8;               // fragment base (ushort units)

    // operand bases; frag(kk,p) at + kk*1024 + p*256 (ushorts)
    const unsigned short* ar = in1F + (size_t)(b * HH + yo) * 16384 + lofs;
    const unsigned short* br_[2];
    br_[0] = in2F + (size_t)(b * HH + (vs_[0] ? ys0 : 0)) * 16384 + lofs;
    br_[1] = in2F + (size_t)(b * HH + (vs_[1] ? ys1 : 0)) * 16384 + lofs;

    // ---- depth-4 / distance-3 rings for BOTH A and B (proven pattern) ----
    bf16x8 Ab[4][2], Bb[4][2][2];
    #pragma unroll
    for (int s = 0; s < 3; ++s) {
        #pragma unroll
        for (int p = 0; p < 2; ++p)
            Ab[s][p] = *(const bf16x8*)(ar + s * 1024 + p * 256);
        #pragma unroll
        for (int jj = 0; jj < 2; ++jj)
            if (vs_[jj])
                #pragma unroll
                for (int p = 0; p < 2; ++p)
                    Bb[s][jj][p] = *(const bf16x8*)(br_[jj] + s * 1024 + p * 256);
    }

    f32x16 acc[2][2];                            // [jj][parity]
    #pragma unroll
    for (int jj = 0; jj < 2; ++jj)
        #pragma unroll
        for (int p = 0; p < 2; ++p)
            acc[jj][p] = (f32x16)(0.0f);

    #pragma unroll
    for (int kk = 0; kk < 16; ++kk) {
        if (kk < 13) {                           // refill slot kk+3, 3 iters ahead
            #pragma unroll
            for (int p = 0; p < 2; ++p)
                Ab[(kk + 3) & 3][p] =
                    *(const bf16x8*)(ar + (size_t)(kk + 3) * 1024 + p * 256);
            #pragma unroll
            for (int jj = 0; jj < 2; ++jj)
                if (vs_[jj])
                    #pragma unroll
                    for (int p = 0; p < 2; ++p)
                        Bb[(kk + 3) & 3][jj][p] =
                            *(const bf16x8*)(br_[jj] + (size_t)(kk + 3) * 1024 + p * 256);
        }
        #pragma unroll
        for (int jj = 0; jj < 2; ++jj)
            if (vs_[jj])
                #pragma unroll
                for (int p = 0; p < 2; ++p)
                    acc[jj][p] = __builtin_amdgcn_mfma_f32_32x32x16_bf16(
                        Ab[kk & 3][p], Bb[kk & 3][jj][p], acc[jj][p], 0, 0, 0);
    }

    // Epilogue: wave-private D^T dump + band extract, j0 then j1.
    // 32x32 C layout: col = l31 (n = ce), row = (r&3) + 8*(r>>2) + 4*q2 (m = xe).
    // Invalid-ysrc jj falls through with acc == 0 -> stores zeros (required).
    float* dtw = dts[w];
    int xe = lane >> 1;
    int pe = lane & 1;
    #pragma unroll
    for (int jj = 0; jj < 2; ++jj) {
        int j = j0 + jj;
        if (j > 20) continue;                    // q=10 has no j1
        float* orow = out + (((size_t)(b * 441 + j * GW)) * HH + yo) * WW;
        #pragma unroll
        for (int p = 0; p < 2; ++p)
            #pragma unroll
            for (int rq = 0; rq < 4; ++rq) {
                f32x4 v = { acc[jj][p][4 * rq], acc[jj][p][4 * rq + 1],
                            acc[jj][p][4 * rq + 2], acc[jj][p][4 * rq + 3] };
                *(f32x4*)(dtw + (size_t)(p * 32 + l31) * 36 + rq * 8 + q2 * 4) = v;
            }
        #pragma unroll
        for (int jx = 0; jx < GW; ++jx) {
            int ce = xe + jx - 10;               // x = 2*xe+pe, colx = 2*ce+pe
            float val = (ce >= 0 && ce < 32)
                      ? dtw[(size_t)(pe * 32 + ce) * 36 + xe] : 0.0f;
            __builtin_nontemporal_store(val, orow + (size_t)jx * HW + lane);
        }
    }
}

extern "C" void kernel_launch(void* const* d_in, const int* in_sizes, int n_in,
                              void* d_out, int out_size, void* d_ws, size_t ws_size,
                              hipStream_t stream)
{
    (void)in_sizes; (void)n_in; (void)out_size; (void)ws_size;
    const float* in1 = (const float*)d_in[0];
    const float* in2 = (const float*)d_in[1];
    float* out = (float*)d_out;

    unsigned short* in1F = (unsigned short*)d_ws;                 // 12.6 MB
    unsigned short* in2F = in1F + (size_t)NB * HW * CC;           // 12.6 MB

    prep_kernel<<<dim3(1536), dim3(256), 0, stream>>>(in1, in2, in1F, in2F);
    corr_kernel<<<dim3(NB * 88 * 3), dim3(256), 0, stream>>>(in1F, in2F, out);
}